// Round 18
// baseline (38.594 us; speedup 1.0000x reference)
//
#include <hip/hip_runtime.h>
#include <math.h>

#define NCH 256        // number of simplex chunks (grid_ect = 2*NCH = 512)
#define RSL 8          // reduction slices
#define FPS 32768.0f   // fixed-point scale 2^15 for transition sums

// K0: materialize per-simplex records so the hot kernel streams sequentially.
// Edge e -> erec[2e]   = {x0,y0,z0, bitcast(g)}, erec[2e+1] = {x1,y1,z1, 0}
// Face f -> frec[3f]   = {x0,y0,z0, bitcast(g)}, frec[3f+1/2] = verts 1/2.
// Random x gathers happen HERE once (480KB footprint, L2-absorbed);
// writes are linear. E+F threads.
__global__ __launch_bounds__(256) void prep_kernel(const float* __restrict__ x,
    const int* __restrict__ ei, const int* __restrict__ face,
    const int* __restrict__ batch, float4* __restrict__ erec,
    float4* __restrict__ frec, int E, int F) {
  int m = blockIdx.x * 256 + threadIdx.x;
  if (m < E) {
    int n0 = ei[m], n1 = ei[E + m];
    int g = batch[n0];
    erec[2 * m]     = float4{x[3 * n0], x[3 * n0 + 1], x[3 * n0 + 2],
                             __int_as_float(g)};
    erec[2 * m + 1] = float4{x[3 * n1], x[3 * n1 + 1], x[3 * n1 + 2], 0.f};
  } else if (m < E + F) {
    int f = m - E;
    int n0 = face[f], n1 = face[F + f], n2 = face[2 * F + f];
    int g = batch[n0];
    frec[3 * f]     = float4{x[3 * n0], x[3 * n0 + 1], x[3 * n0 + 2],
                             __int_as_float(g)};
    frec[3 * f + 1] = float4{x[3 * n1], x[3 * n1 + 1], x[3 * n1 + 2], 0.f};
    frec[3 * f + 2] = float4{x[3 * n2], x[3 * n2 + 1], x[3 * n2 + 2], 0.f};
  }
}

// K1: saturation-split ECT over PURELY SEQUENTIAL inputs (r16 diagnosis:
// cold-replay premium ~18us came from first-touch random gathers; records
// are now pre-gathered in simplex order). Block = (chunk c, theta-half hf);
// 1024 threads = (srow 0..63, t16 0..15); 2 blocks/CU = 8 waves/SIMD.
// Single-bin deposit (2w<1 -> <=1 transition bin, r14-proven).
// LDS hist [arr][g][bin][t16] = 32 KB; LDS int atomics only (deterministic).
// Flush = plain coalesced int4 stores into partial[bid][8192].
__global__ __launch_bounds__(1024) void ect_kernel(const float* __restrict__ x,
    const float* __restrict__ v, const float4* __restrict__ erec,
    const float4* __restrict__ frec, const int* __restrict__ batch,
    const float* __restrict__ lin, const int* __restrict__ scale_p,
    int* __restrict__ partial, int N, int E, int F, int M, int csz) {
  __shared__ alignas(16) int hist[8192];  // arr*4096 + g*512 + bin*16 + t16
  int tid = threadIdx.x, bid = blockIdx.x;
  int c = bid >> 1, hf = bid & 1;
#pragma unroll
  for (int i = 0; i < 2; ++i)
    ((int4*)hist)[tid + 1024 * i] = int4{0, 0, 0, 0};
  __syncthreads();

  int t16 = tid & 15, srow = tid >> 4;    // srow 0..63
  int tt = (hf << 4) + t16;               // global theta
  float v0 = v[tt], v1 = v[32 + tt], v2 = v[64 + tt];
  int start = c * csz;
  int end = min(start + csz, M);

  float scale = (float)scale_p[0];
  float lin0 = lin[0];
  float step = (lin[31] - lin0) * (1.f / 31.f);
  float istep = 1.f / step;
  float Cl = scale * step * 1.44269504088896f;  // log2-slope per bin
  float w = 13.f / (scale * step);              // transition half-width (bins)

  auto dotv = [&](float4 r) {
    return fmaf(r.x, v0, fmaf(r.y, v1, r.z * v2));
  };
  auto deposit = [&](float h, int g, int isn) {
    float kf = (h - lin0) * istep;
    int fs = max((int)floorf(kf + w) + 1, 0);
    int gb = g << 9;
    if (fs <= 31) atomicAdd(&hist[gb + (fs << 4) + t16], isn);
    float bf = rintf(kf);
    float d = kf - bf;
    if (fabsf(d) <= w) {
      int b = (int)bf;
      if ((unsigned)b <= 31u) {
        float e2 = __builtin_amdgcn_exp2f(Cl * d);
        float val = (float)isn * __builtin_amdgcn_rcpf(1.f + e2);
        atomicAdd(&hist[4096 + gb + (b << 4) + t16], (int)rintf(val * FPS));
      }
    }
  };

  // nodes: x + batch read linearly
  int e0 = min(end, N);
  for (int m = start + srow; m < e0; m += 64) {
    float h = fmaf(x[3 * m], v0, fmaf(x[3 * m + 1], v1, x[3 * m + 2] * v2));
    deposit(h, batch[m], 1);
  }
  // edges: sequential float4 record stream, sign -1
  int s1 = max(start, N), e1 = min(end, N + E);
  for (int m = s1 + srow; m < e1; m += 64) {
    int e = m - N;
    float4 r0 = erec[2 * e], r1 = erec[2 * e + 1];
    deposit(fmaxf(dotv(r0), dotv(r1)), __float_as_int(r0.w), -1);
  }
  // faces: sequential float4 record stream, sign +1
  int s2 = max(start, N + E);
  for (int m = s2 + srow; m < end; m += 64) {
    int f = m - N - E;
    float4 r0 = frec[3 * f], r1 = frec[3 * f + 1], r2 = frec[3 * f + 2];
    deposit(fmaxf(fmaxf(dotv(r0), dotv(r1)), dotv(r2)),
            __float_as_int(r0.w), 1);
  }
  __syncthreads();
  int4* dst = (int4*)(partial + (size_t)bid * 8192);
  const int4* src = (const int4*)hist;
#pragma unroll
  for (int i = 0; i < 2; ++i)
    dst[tid + 1024 * i] = src[tid + 1024 * i];
}

// K2: tree reduce over chunks. 512 blocks: s = bid>>6 (0..7), cg = bid&63;
// cell cid = cg*256+tid; cid = hf*8192 + (arr*4096 + g*512 + bin*16 + t16).
__global__ __launch_bounds__(256) void reduce_kernel(const int* __restrict__ partial,
    int* __restrict__ part2) {
  int tid = threadIdx.x, bid = blockIdx.x;
  int s = bid >> 6, cg = bid & 63;
  int cid = cg * 256 + tid;
  int hf = cid >> 13, j = cid & 8191;
  int sum = 0;
  for (int cc = s; cc < NCH; cc += RSL)
    sum += partial[(size_t)(cc * 2 + hf) * 8192 + j];
  part2[s * 16384 + cid] = sum;
}

// K3: per-graph block (8 x 1024): sum RSL slices, Hillis-Steele prefix of
// markers over bins, add fractional transitions, per-graph max, normalize.
__global__ __launch_bounds__(1024) void fin_kernel(const int* __restrict__ part2,
    float* __restrict__ out) {
  __shared__ float sP[32][33];
  __shared__ float wmax[16];
  int g = blockIdx.x, tid = threadIdx.x;
  int b = tid >> 5, t = tid & 31;
  int hf = t >> 4, t16 = t & 15;
  int jc = (hf << 13) + (g << 9) + (b << 4) + t16;  // marker cell
  int ja = jc + 4096;                               // transition cell
  int sc = 0, sa = 0;
#pragma unroll
  for (int s = 0; s < RSL; ++s) {
    sc += part2[s * 16384 + jc];
    sa += part2[s * 16384 + ja];
  }
  sP[b][t] = (float)sc;
  __syncthreads();
#pragma unroll
  for (int st = 1; st < 32; st <<= 1) {
    float add = (b >= st) ? sP[b - st][t] : 0.f;
    __syncthreads();
    sP[b][t] += add;
    __syncthreads();
  }
  float r = sP[b][t] + (float)sa * (1.f / FPS);
  float m = r;
#pragma unroll
  for (int off = 32; off > 0; off >>= 1) m = fmaxf(m, __shfl_down(m, off));
  if ((tid & 63) == 0) wmax[tid >> 6] = m;
  __syncthreads();
  if (tid == 0) {
    float mm = wmax[0];
#pragma unroll
    for (int ww = 1; ww < 16; ++ww) mm = fmaxf(mm, wmax[ww]);
    wmax[0] = mm;
  }
  __syncthreads();
  out[(size_t)g * 1024 + tid] = r / wmax[0];
}

extern "C" void kernel_launch(void* const* d_in, const int* in_sizes, int n_in,
                              void* d_out, int out_size, void* d_ws, size_t ws_size,
                              hipStream_t stream) {
  const float* x     = (const float*)d_in[0];
  const float* v     = (const float*)d_in[1];
  const float* lin   = (const float*)d_in[2];
  const int*   ei    = (const int*)d_in[3];
  const int*   face  = (const int*)d_in[4];
  const int*   batch = (const int*)d_in[5];
  const int*   scale = (const int*)d_in[6];
  const int N = in_sizes[5];
  const int E = in_sizes[3] / 2;
  const int F = in_sizes[4] / 3;
  const int M = N + E + F;
  const int csz = (M + NCH - 1) / NCH;   // simplices per chunk (~704)

  int*    partial = (int*)d_ws;                         // 2*NCH*8192 ints
  int*    part2   = partial + (size_t)2 * NCH * 8192;   // RSL*16384 ints
  float4* erec    = (float4*)(part2 + RSL * 16384);     // 2E float4
  float4* frec    = erec + (size_t)2 * E;               // 3F float4

  prep_kernel<<<(E + F + 255) / 256, 256, 0, stream>>>(x, ei, face, batch,
                                                       erec, frec, E, F);
  ect_kernel<<<2 * NCH, 1024, 0, stream>>>(x, v, erec, frec, batch, lin, scale,
                                           partial, N, E, F, M, csz);
  reduce_kernel<<<64 * RSL, 256, 0, stream>>>(partial, part2);
  fin_kernel<<<8, 1024, 0, stream>>>(part2, (float*)d_out);
}

// Round 19
// 32.650 us; speedup vs baseline: 1.1820x; 1.1820x over previous
//
#include <hip/hip_runtime.h>
#include <math.h>

#define NCH 256        // number of simplex chunks (grid_ect = 2*NCH = 512)
#define RSL 8          // reduction slices
#define FPS 32768.0f   // fixed-point scale 2^15 for transition sums

typedef int iv4 __attribute__((ext_vector_type(4)));

// K1: r12's ect EXACTLY, with ONE change: the 32KB/block flush uses
// nontemporal stores so the 16.8MB partial stream does not allocate in the
// per-XCD L2. Theory (r16-r18 accounting): per-XCD working set = inputs
// 2.6MB (random-gathered, needed every replay) + partial 2.1MB > 4MB L2;
// partial evicts inputs each replay -> ect's first pass runs L2-cold
// (27us vs 8.8us hot). Keeping partial out of L2 keeps inputs resident.
__global__ __launch_bounds__(1024) void ect_kernel(const float* __restrict__ x,
    const float* __restrict__ v, const int* __restrict__ ei,
    const int* __restrict__ face, const int* __restrict__ batch,
    const float* __restrict__ lin, const int* __restrict__ scale_p,
    int* __restrict__ partial, int N, int E, int F, int M, int csz) {
  __shared__ alignas(16) int hist[8192];  // arr*4096 + g*512 + bin*16 + t16
  int tid = threadIdx.x, bid = blockIdx.x;
  int c = bid >> 1, hf = bid & 1;
#pragma unroll
  for (int i = 0; i < 2; ++i)
    ((int4*)hist)[tid + 1024 * i] = int4{0, 0, 0, 0};
  __syncthreads();

  int t16 = tid & 15, srow = tid >> 4;    // srow 0..63
  int tt = (hf << 4) + t16;               // global theta
  float v0 = v[tt], v1 = v[32 + tt], v2 = v[64 + tt];
  int start = c * csz;
  int end = min(start + csz, M);

  float scale = (float)scale_p[0];
  float lin0 = lin[0];
  float step = (lin[31] - lin0) * (1.f / 31.f);
  float istep = 1.f / step;
  float Cl = scale * step * 1.44269504088896f;  // log2-slope per bin
  float w = 13.f / (scale * step);              // transition half-width (bins)

  auto dot3 = [&](int n) {
    return fmaf(x[3 * n], v0, fmaf(x[3 * n + 1], v1, x[3 * n + 2] * v2));
  };
  auto deposit = [&](float h, int g, int isn) {
    float kf = (h - lin0) * istep;
    int b0 = (int)ceilf(kf - w);
    int b1 = (int)floorf(kf + w);
    int fs = max(b1 + 1, 0);
    int gb = g << 9;
    if (fs <= 31) atomicAdd(&hist[gb + (fs << 4) + t16], isn);
    float q = Cl * kf;
    float fsn = (float)isn;
    int blo = max(b0, 0), bhi = min(b1, 31);
    for (int b = blo; b <= bhi; ++b) {
      float e2 = __builtin_amdgcn_exp2f(fmaf(-Cl, (float)b, q));
      float val = fsn * __builtin_amdgcn_rcpf(1.f + e2);
      atomicAdd(&hist[4096 + gb + (b << 4) + t16], (int)rintf(val * FPS));
    }
  };

  // nodes
  int e0 = min(end, N);
  for (int m = start + srow; m < e0; m += 64)
    deposit(dot3(m), batch[m], 1);
  // edges (max over 2 endpoints, sign -1)
  int s1 = max(start, N), e1 = min(end, N + E);
  for (int m = s1 + srow; m < e1; m += 64) {
    int e = m - N;
    int n0 = ei[e], n1 = ei[E + e];
    deposit(fmaxf(dot3(n0), dot3(n1)), batch[n0], -1);
  }
  // faces (max over 3 vertices, sign +1)
  int s2 = max(start, N + E);
  for (int m = s2 + srow; m < end; m += 64) {
    int f = m - N - E;
    int n0 = face[f], n1 = face[F + f], n2 = face[2 * F + f];
    deposit(fmaxf(fmaxf(dot3(n0), dot3(n1)), dot3(n2)), batch[n0], 1);
  }
  __syncthreads();
  // flush: NONTEMPORAL int4 stores — keep partial out of L2
  iv4* dst = (iv4*)(partial + (size_t)bid * 8192);
  const iv4* src = (const iv4*)hist;
#pragma unroll
  for (int i = 0; i < 2; ++i)
    __builtin_nontemporal_store(src[tid + 1024 * i], &dst[tid + 1024 * i]);
}

// K2: tree reduce over chunks (unchanged r12; plain loads — streaming,
// bandwidth-tolerant). 512 blocks: s = bid>>6, cg = bid&63; cid = cg*256+tid.
__global__ __launch_bounds__(256) void reduce_kernel(const int* __restrict__ partial,
    int* __restrict__ part2) {
  int tid = threadIdx.x, bid = blockIdx.x;
  int s = bid >> 6, cg = bid & 63;
  int cid = cg * 256 + tid;
  int hf = cid >> 13, j = cid & 8191;
  int sum = 0;
  for (int cc = s; cc < NCH; cc += RSL)
    sum += partial[(size_t)(cc * 2 + hf) * 8192 + j];
  part2[s * 16384 + cid] = sum;
}

// K3: per-graph block (8 x 1024): sum RSL slices, Hillis-Steele prefix of
// markers over bins, add fractional transitions, per-graph max, normalize.
__global__ __launch_bounds__(1024) void fin_kernel(const int* __restrict__ part2,
    float* __restrict__ out) {
  __shared__ float sP[32][33];
  __shared__ float wmax[16];
  int g = blockIdx.x, tid = threadIdx.x;
  int b = tid >> 5, t = tid & 31;
  int hf = t >> 4, t16 = t & 15;
  int jc = (hf << 13) + (g << 9) + (b << 4) + t16;  // marker cell
  int ja = jc + 4096;                               // transition cell
  int sc = 0, sa = 0;
#pragma unroll
  for (int s = 0; s < RSL; ++s) {
    sc += part2[s * 16384 + jc];
    sa += part2[s * 16384 + ja];
  }
  sP[b][t] = (float)sc;
  __syncthreads();
#pragma unroll
  for (int st = 1; st < 32; st <<= 1) {
    float add = (b >= st) ? sP[b - st][t] : 0.f;
    __syncthreads();
    sP[b][t] += add;
    __syncthreads();
  }
  float r = sP[b][t] + (float)sa * (1.f / FPS);
  float m = r;
#pragma unroll
  for (int off = 32; off > 0; off >>= 1) m = fmaxf(m, __shfl_down(m, off));
  if ((tid & 63) == 0) wmax[tid >> 6] = m;
  __syncthreads();
  if (tid == 0) {
    float mm = wmax[0];
#pragma unroll
    for (int ww = 1; ww < 16; ++ww) mm = fmaxf(mm, wmax[ww]);
    wmax[0] = mm;
  }
  __syncthreads();
  out[(size_t)g * 1024 + tid] = r / wmax[0];
}

extern "C" void kernel_launch(void* const* d_in, const int* in_sizes, int n_in,
                              void* d_out, int out_size, void* d_ws, size_t ws_size,
                              hipStream_t stream) {
  const float* x     = (const float*)d_in[0];
  const float* v     = (const float*)d_in[1];
  const float* lin   = (const float*)d_in[2];
  const int*   ei    = (const int*)d_in[3];
  const int*   face  = (const int*)d_in[4];
  const int*   batch = (const int*)d_in[5];
  const int*   scale = (const int*)d_in[6];
  const int N = in_sizes[5];
  const int E = in_sizes[3] / 2;
  const int F = in_sizes[4] / 3;
  const int M = N + E + F;
  const int csz = (M + NCH - 1) / NCH;   // simplices per chunk (~704)

  int* partial = (int*)d_ws;                          // 2*NCH*8192 ints
  int* part2   = partial + (size_t)2 * NCH * 8192;    // RSL*16384 ints

  ect_kernel<<<2 * NCH, 1024, 0, stream>>>(x, v, ei, face, batch, lin, scale,
                                           partial, N, E, F, M, csz);
  reduce_kernel<<<64 * RSL, 256, 0, stream>>>(partial, part2);
  fin_kernel<<<8, 1024, 0, stream>>>(part2, (float*)d_out);
}